// Round 2
// baseline (315.084 us; speedup 1.0000x reference)
//
#include <hip/hip_runtime.h>
#include <hip/hip_bf16.h>

typedef __bf16 bf16_t;
typedef __bf16 bf16x8 __attribute__((ext_vector_type(8)));
typedef float f32x4 __attribute__((ext_vector_type(4)));

#define N_NODES 8192
#define N_EDGES 131072
#define BATCH   2
#define HDIM    256
#define M_ROWS  (BATCH * N_NODES)  // 16384

// ---- ws layout (bytes), all offsets 256B-aligned ----
// h_f32   : 0          (16,777,216)
// m_bf16  : 16777216   (8,388,608)
// WneT    : 25165824   (65,536)   bf16 [256 cols][128 k]
// WconvT  : 25231360   (393,216)  bf16 [3][256 cols][256 k]
// row_ptr : 25624576   (32,772)
// ds      : 25690112   (65,536)
// dd      : 25755648   (65,536)
// pg_part : 25821184   (4,096)    total ~24.6 MiB

__global__ __launch_bounds__(256) void rowptr_kernel(const int* __restrict__ src, int* __restrict__ rp) {
  int i = blockIdx.x * blockDim.x + threadIdx.x;
  if (i > N_NODES) return;
  if (i == N_NODES) { rp[i] = N_EDGES; return; }
  int lo = 0, hi = N_EDGES;
  while (lo < hi) { int mid = (lo + hi) >> 1; if (src[mid] < i) lo = mid + 1; else hi = mid; }
  rp[i] = lo;
}

// fp32 weights -> bf16 transposed copies for MFMA B-operand.
__global__ __launch_bounds__(256) void transpose_w(const float* __restrict__ Wne,
                                                   const float* __restrict__ Wconv,
                                                   bf16_t* __restrict__ WneT,
                                                   bf16_t* __restrict__ WconvT) {
  int t = blockIdx.x * blockDim.x + threadIdx.x;
  if (t < 256 * 128) {
    int n = t / 128, k = t % 128;
    WneT[t] = (bf16_t)Wne[k * 256 + n];
  } else {
    int u = t - 256 * 128;
    if (u < 3 * 256 * 256) {
      int l = u / 65536, r = u % 65536;
      int n = r / 256, k = r % 256;
      WconvT[l * 65536 + n * 256 + k] = (bf16_t)Wconv[l * 65536 + k * 256 + n];
    }
  }
}

// C[M x 256] = relu(A[M x K] @ B[K x 256] + bias)  (+ H if FUSE), H is f32 master.
// BT is bf16 B transposed: BT[col][k]. One wave per 16x16 tile; block = 4 waves = 64 cols.
// AF32: A is fp32 (converted to bf16 in-register); else A is bf16.
template<int K, bool FUSE, bool AF32>
__global__ __launch_bounds__(256) void gemm_relu(const void* __restrict__ Av,
                                                 const bf16_t* __restrict__ BT,
                                                 const float* __restrict__ bias,
                                                 float* __restrict__ H) {
  int lane = threadIdx.x & 63;
  int wv = threadIdx.x >> 6;
  int r0 = blockIdx.x * 16;
  int c0 = blockIdx.y * 64 + wv * 16;
  int l15 = lane & 15, l4 = lane >> 4;
  const bf16_t* Bp = BT + (size_t)(c0 + l15) * K + 8 * l4;
  f32x4 acc = {0.f, 0.f, 0.f, 0.f};
  if (AF32) {
    const float* Ap = (const float*)Av + (size_t)(r0 + l15) * K + 8 * l4;
#pragma unroll
    for (int kk = 0; kk < K; kk += 32) {
      f32x4 a0 = *(const f32x4*)(Ap + kk);
      f32x4 a1 = *(const f32x4*)(Ap + kk + 4);
      bf16x8 a;
#pragma unroll
      for (int j = 0; j < 4; ++j) { a[j] = (bf16_t)a0[j]; a[4 + j] = (bf16_t)a1[j]; }
      bf16x8 b = *(const bf16x8*)(Bp + kk);
      acc = __builtin_amdgcn_mfma_f32_16x16x32_bf16(a, b, acc, 0, 0, 0);
    }
  } else {
    const bf16_t* Ap = (const bf16_t*)Av + (size_t)(r0 + l15) * K + 8 * l4;
#pragma unroll
    for (int kk = 0; kk < K; kk += 32) {
      bf16x8 a = *(const bf16x8*)(Ap + kk);
      bf16x8 b = *(const bf16x8*)(Bp + kk);
      acc = __builtin_amdgcn_mfma_f32_16x16x32_bf16(a, b, acc, 0, 0, 0);
    }
  }
  int col = c0 + l15;
  float bv = bias[col];
#pragma unroll
  for (int i = 0; i < 4; ++i) {
    int row = r0 + 4 * l4 + i;
    size_t idx = (size_t)row * HDIM + col;
    float v = fmaxf(acc[i] + bv, 0.f);
    if (FUSE) v += H[idx];
    H[idx] = v;
  }
}

// m[b,i,:] = sum over edges with src==i of h[b, dst[e], :]; rounded to bf16 for MFMA.
__global__ __launch_bounds__(256) void gather_kernel(const float* __restrict__ h,
                                                     const int* __restrict__ rp,
                                                     const int* __restrict__ dst,
                                                     bf16_t* __restrict__ m) {
  int t = threadIdx.x;                    // column 0..255
  int gid = blockIdx.x;                   // 0..2047
  int b = gid >> 10;
  int i0 = (gid & 1023) * 8;
  const float* hb = h + (size_t)b * N_NODES * HDIM;
  bf16_t* mb = m + (size_t)b * N_NODES * HDIM;
  for (int r = 0; r < 8; ++r) {
    int i = i0 + r;
    int e0 = rp[i], e1 = rp[i + 1];
    float acc = 0.f;
    for (int e = e0; e < e1; ++e) {
      int j = dst[e];
      acc += hb[(size_t)j * HDIM + t];
    }
    mb[(size_t)i * HDIM + t] = (bf16_t)acc;
  }
}

__device__ inline float wred(float v) {
#pragma unroll
  for (int m = 32; m; m >>= 1) v += __shfl_xor(v, m);
  return v;
}

// Per node: node_health (5 dots), ds=dot(h,Wep[:256]), dd=dot(h,Wep[256:]), pg partial, h copy out.
__global__ __launch_bounds__(256) void node_out(const float* __restrict__ h,
                                                const float* __restrict__ Wcls,
                                                const float* __restrict__ bcls,
                                                const float* __restrict__ Wep,
                                                const float* __restrict__ Wgp,
                                                float* __restrict__ ds, float* __restrict__ dd,
                                                float* __restrict__ pg_part,
                                                float* __restrict__ out_nh,
                                                float* __restrict__ out_h) {
  int lane = threadIdx.x & 63;
  int gw = blockIdx.x * 4 + (threadIdx.x >> 6);  // 0..1023, 16 rows each
  int row0 = gw * 16;
  float wc[4][5], wsv[4], wdv[4], wgv[4];
#pragma unroll
  for (int j = 0; j < 4; ++j) {
    int k = 4 * lane + j;
#pragma unroll
    for (int c = 0; c < 5; ++c) wc[j][c] = Wcls[k * 5 + c];
    wsv[j] = Wep[k];
    wdv[j] = Wep[256 + k];
    wgv[j] = Wgp[k];
  }
  float bc[5];
#pragma unroll
  for (int c = 0; c < 5; ++c) bc[c] = bcls[c];
  float pg_acc = 0.f;
  for (int n = 0; n < 16; ++n) {
    int row = row0 + n;
    const float4 x = *(const float4*)(h + (size_t)row * HDIM + 4 * lane);
    float xs[4] = {x.x, x.y, x.z, x.w};
    float pc0 = 0, pc1 = 0, pc2 = 0, pc3 = 0, pc4 = 0, ps = 0, pd = 0, pg = 0;
#pragma unroll
    for (int j = 0; j < 4; ++j) {
      float xv = xs[j];
      pc0 += xv * wc[j][0]; pc1 += xv * wc[j][1]; pc2 += xv * wc[j][2];
      pc3 += xv * wc[j][3]; pc4 += xv * wc[j][4];
      ps += xv * wsv[j]; pd += xv * wdv[j]; pg += xv * wgv[j];
    }
    *(float4*)(out_h + (size_t)row * HDIM + 4 * lane) = x;
    pg_acc += pg;
    pc0 = wred(pc0); pc1 = wred(pc1); pc2 = wred(pc2); pc3 = wred(pc3); pc4 = wred(pc4);
    ps = wred(ps); pd = wred(pd);
    if (lane == 0) {
      out_nh[(size_t)row * 5 + 0] = pc0 + bc[0];
      out_nh[(size_t)row * 5 + 1] = pc1 + bc[1];
      out_nh[(size_t)row * 5 + 2] = pc2 + bc[2];
      out_nh[(size_t)row * 5 + 3] = pc3 + bc[3];
      out_nh[(size_t)row * 5 + 4] = pc4 + bc[4];
      ds[row] = ps;
      dd[row] = pd;
    }
  }
  float g = wred(pg_acc);
  if (lane == 0) pg_part[gw] = g;
}

__global__ __launch_bounds__(256) void edge_out(const float* __restrict__ ds,
                                                const float* __restrict__ dd,
                                                const int* __restrict__ src,
                                                const int* __restrict__ dst,
                                                const float* __restrict__ bep,
                                                float* __restrict__ out_ep) {
  int t = blockIdx.x * blockDim.x + threadIdx.x;  // < 262144
  int b = t >> 17;
  int e = t & (N_EDGES - 1);
  float v = ds[(b << 13) + src[e]] + dd[(b << 13) + dst[e]] + bep[0];
  out_ep[t] = 1.f / (1.f + expf(-v));
}

__global__ void sys_out(const float* __restrict__ pg_part, const float* __restrict__ bgp,
                        float* __restrict__ out_sys) {
  int b = blockIdx.x, t = threadIdx.x;  // 256 threads
  float v = pg_part[b * 512 + t] + pg_part[b * 512 + 256 + t];
#pragma unroll
  for (int m = 32; m; m >>= 1) v += __shfl_xor(v, m);
  __shared__ float s[4];
  if ((t & 63) == 0) s[t >> 6] = v;
  __syncthreads();
  if (t == 0) {
    float tot = s[0] + s[1] + s[2] + s[3];
    float g = tot / (float)N_NODES + bgp[0];
    out_sys[b] = 1.f / (1.f + expf(-g));
  }
}

extern "C" void kernel_launch(void* const* d_in, const int* in_sizes, int n_in,
                              void* d_out, int out_size, void* d_ws, size_t ws_size,
                              hipStream_t stream) {
  (void)in_sizes; (void)n_in; (void)out_size; (void)ws_size;
  const float* nf    = (const float*)d_in[0];
  const int*   src   = (const int*)d_in[3];
  const int*   dst   = (const int*)d_in[4];
  const float* Wne   = (const float*)d_in[5];
  const float* bne   = (const float*)d_in[6];
  const float* Wconv = (const float*)d_in[9];
  const float* bconv = (const float*)d_in[10];
  const float* Wcls  = (const float*)d_in[11];
  const float* bcls  = (const float*)d_in[12];
  const float* Wep   = (const float*)d_in[13];
  const float* bep   = (const float*)d_in[14];
  const float* Wgp   = (const float*)d_in[15];
  const float* bgp   = (const float*)d_in[16];

  char* ws = (char*)d_ws;
  float*  h_f32   = (float*)(ws + 0);
  bf16_t* m_bf16  = (bf16_t*)(ws + 16777216);
  bf16_t* WneT    = (bf16_t*)(ws + 25165824);
  bf16_t* WconvT  = (bf16_t*)(ws + 25231360);
  int*    rp      = (int*)(ws + 25624576);
  float*  ds      = (float*)(ws + 25690112);
  float*  dd      = (float*)(ws + 25755648);
  float*  pg      = (float*)(ws + 25821184);

  float* out     = (float*)d_out;
  float* out_nh  = out;            // 81920
  float* out_ep  = out + 81920;    // 262144
  float* out_sys = out + 344064;   // 2
  float* out_h   = out + 344066;   // 4194304

  hipLaunchKernelGGL(rowptr_kernel, dim3(33), dim3(256), 0, stream, src, rp);
  hipLaunchKernelGGL(transpose_w, dim3(896), dim3(256), 0, stream, Wne, Wconv, WneT, WconvT);
  hipLaunchKernelGGL((gemm_relu<128, false, true>), dim3(1024, 4), dim3(256), 0, stream,
                     nf, WneT, bne, h_f32);
  for (int l = 0; l < 3; ++l) {
    hipLaunchKernelGGL(gather_kernel, dim3(2048), dim3(256), 0, stream, h_f32, rp, dst, m_bf16);
    hipLaunchKernelGGL((gemm_relu<256, true, false>), dim3(1024, 4), dim3(256), 0, stream,
                       m_bf16, WconvT + l * 65536, bconv + l * 256, h_f32);
  }
  hipLaunchKernelGGL(node_out, dim3(256), dim3(256), 0, stream, h_f32, Wcls, bcls, Wep, Wgp,
                     ds, dd, pg, out_nh, out_h);
  hipLaunchKernelGGL(edge_out, dim3(1024), dim3(256), 0, stream, ds, dd, src, dst, bep, out_ep);
  hipLaunchKernelGGL(sys_out, dim3(2), dim3(256), 0, stream, pg, bgp, out_sys);
}

// Round 3
// 185.978 us; speedup vs baseline: 1.6942x; 1.6942x over previous
//
#include <hip/hip_runtime.h>
#include <hip/hip_bf16.h>

typedef __bf16 bf16_t;
typedef __bf16 bf16x2 __attribute__((ext_vector_type(2)));
typedef __bf16 bf16x8 __attribute__((ext_vector_type(8)));
typedef float f32x4 __attribute__((ext_vector_type(4)));

#define N_NODES 8192
#define N_EDGES 131072
#define BATCH   2
#define HDIM    256
#define M_ROWS  (BATCH * N_NODES)  // 16384

// ---- ws layout (bytes), shadow variant (needs 34,213,888 B) ----
// h_f32   : 0          (16,777,216)
// m_bf16  : 16777216   (8,388,608)
// h_bf16  : 25165824   (8,388,608)   gather-read shadow
// WneT    : 33554432   (65,536)
// WconvT  : 33619968   (393,216)
// rp      : 34013184   (32,772)
// ds      : 34078720   (65,536)
// dd      : 34144256   (65,536)
// pg      : 34209792   (4,096)
// fallback (no h_bf16): same order minus shadow, as in round 2.

__global__ __launch_bounds__(256) void rowptr_kernel(const int* __restrict__ src, int* __restrict__ rp) {
  int i = blockIdx.x * blockDim.x + threadIdx.x;
  if (i > N_NODES) return;
  if (i == N_NODES) { rp[i] = N_EDGES; return; }
  int lo = 0, hi = N_EDGES;
  while (lo < hi) { int mid = (lo + hi) >> 1; if (src[mid] < i) lo = mid + 1; else hi = mid; }
  rp[i] = lo;
}

__global__ __launch_bounds__(256) void transpose_w(const float* __restrict__ Wne,
                                                   const float* __restrict__ Wconv,
                                                   bf16_t* __restrict__ WneT,
                                                   bf16_t* __restrict__ WconvT) {
  int t = blockIdx.x * blockDim.x + threadIdx.x;
  if (t < 256 * 128) {
    int n = t / 128, k = t % 128;
    WneT[t] = (bf16_t)Wne[k * 256 + n];
  } else {
    int u = t - 256 * 128;
    if (u < 3 * 256 * 256) {
      int l = u / 65536, r = u % 65536;
      int n = r / 256, k = r % 256;
      WconvT[l * 65536 + n * 256 + k] = (bf16_t)Wconv[l * 65536 + k * 256 + n];
    }
  }
}

// C = relu(A @ B + bias) [+ Hin residual]; writes f32 Hout and optional bf16 shadow S16.
// A-fragments cached in registers across 4 col-tiles. Grid (256, 4), block = 4 waves.
template<int K, bool FUSE, bool AF32>
__global__ __launch_bounds__(256) void gemm_relu(const void* __restrict__ Av,
                                                 const bf16_t* __restrict__ BT,
                                                 const float* __restrict__ bias,
                                                 const float* __restrict__ Hin,
                                                 float* __restrict__ Hout,
                                                 bf16_t* __restrict__ S16) {
  constexpr int NK = K / 32;
  int lane = threadIdx.x & 63;
  int wv = threadIdx.x >> 6;
  int r0 = (blockIdx.x * 4 + wv) * 16;
  int cg0 = blockIdx.y * 64;
  int l15 = lane & 15, l4 = lane >> 4;
  bf16x8 a[NK];
  if (AF32) {
    const float* Ap = (const float*)Av + (size_t)(r0 + l15) * K + 8 * l4;
#pragma unroll
    for (int kk = 0; kk < NK; ++kk) {
      f32x4 a0 = *(const f32x4*)(Ap + 32 * kk);
      f32x4 a1 = *(const f32x4*)(Ap + 32 * kk + 4);
#pragma unroll
      for (int j = 0; j < 4; ++j) { a[kk][j] = (bf16_t)a0[j]; a[kk][4 + j] = (bf16_t)a1[j]; }
    }
  } else {
    const bf16_t* Ap = (const bf16_t*)Av + (size_t)(r0 + l15) * K + 8 * l4;
#pragma unroll
    for (int kk = 0; kk < NK; ++kk) a[kk] = *(const bf16x8*)(Ap + 32 * kk);
  }
#pragma unroll
  for (int ct = 0; ct < 4; ++ct) {
    int c0 = cg0 + ct * 16;
    const bf16_t* Bp = BT + (size_t)(c0 + l15) * K + 8 * l4;
    f32x4 acc = {0.f, 0.f, 0.f, 0.f};
#pragma unroll
    for (int kk = 0; kk < NK; ++kk)
      acc = __builtin_amdgcn_mfma_f32_16x16x32_bf16(a[kk], *(const bf16x8*)(Bp + 32 * kk), acc, 0, 0, 0);
    int col = c0 + l15;
    float bv = bias[col];
#pragma unroll
    for (int i = 0; i < 4; ++i) {
      int row = r0 + 4 * l4 + i;
      size_t idx = (size_t)row * HDIM + col;
      float v = fmaxf(acc[i] + bv, 0.f);
      if (FUSE) v += Hin[idx];
      Hout[idx] = v;
      if (S16) S16[idx] = (bf16_t)v;
    }
  }
}

// m[b,i,:] = sum over edges src==i of h[b,dst[e],:]. 2 rows/block, 2 cols/thread, 4x unroll.
__global__ __launch_bounds__(256) void gather_b16(const bf16_t* __restrict__ h,
                                                  const int* __restrict__ rp,
                                                  const int* __restrict__ dst,
                                                  bf16_t* __restrict__ m) {
  int tid = threadIdx.x;
  int half = tid >> 7;
  int c = (tid & 127) * 2;
  int gid = blockIdx.x * 2 + half;
  int b = gid >> 13;
  int i = gid & (N_NODES - 1);
  const bf16_t* hb = h + (size_t)b * N_NODES * HDIM + c;
  int e0 = rp[i], e1 = rp[i + 1];
  float a0 = 0.f, a1 = 0.f;
  int e = e0;
  for (; e + 4 <= e1; e += 4) {
    int j0 = dst[e], j1 = dst[e + 1], j2 = dst[e + 2], j3 = dst[e + 3];
    bf16x2 v0 = *(const bf16x2*)(hb + (size_t)j0 * HDIM);
    bf16x2 v1 = *(const bf16x2*)(hb + (size_t)j1 * HDIM);
    bf16x2 v2 = *(const bf16x2*)(hb + (size_t)j2 * HDIM);
    bf16x2 v3 = *(const bf16x2*)(hb + (size_t)j3 * HDIM);
    a0 += (float)v0[0] + (float)v1[0] + (float)v2[0] + (float)v3[0];
    a1 += (float)v0[1] + (float)v1[1] + (float)v2[1] + (float)v3[1];
  }
  for (; e < e1; ++e) {
    int j = dst[e];
    bf16x2 v = *(const bf16x2*)(hb + (size_t)j * HDIM);
    a0 += (float)v[0]; a1 += (float)v[1];
  }
  bf16x2 o; o[0] = (bf16_t)a0; o[1] = (bf16_t)a1;
  *(bf16x2*)(m + (size_t)b * N_NODES * HDIM + (size_t)i * HDIM + c) = o;
}

__global__ __launch_bounds__(256) void gather_f32(const float* __restrict__ h,
                                                  const int* __restrict__ rp,
                                                  const int* __restrict__ dst,
                                                  bf16_t* __restrict__ m) {
  int tid = threadIdx.x;
  int half = tid >> 7;
  int c = (tid & 127) * 2;
  int gid = blockIdx.x * 2 + half;
  int b = gid >> 13;
  int i = gid & (N_NODES - 1);
  const float* hb = h + (size_t)b * N_NODES * HDIM + c;
  int e0 = rp[i], e1 = rp[i + 1];
  float a0 = 0.f, a1 = 0.f;
  int e = e0;
  for (; e + 4 <= e1; e += 4) {
    int j0 = dst[e], j1 = dst[e + 1], j2 = dst[e + 2], j3 = dst[e + 3];
    float2 v0 = *(const float2*)(hb + (size_t)j0 * HDIM);
    float2 v1 = *(const float2*)(hb + (size_t)j1 * HDIM);
    float2 v2 = *(const float2*)(hb + (size_t)j2 * HDIM);
    float2 v3 = *(const float2*)(hb + (size_t)j3 * HDIM);
    a0 += v0.x + v1.x + v2.x + v3.x;
    a1 += v0.y + v1.y + v2.y + v3.y;
  }
  for (; e < e1; ++e) {
    int j = dst[e];
    float2 v = *(const float2*)(hb + (size_t)j * HDIM);
    a0 += v.x; a1 += v.y;
  }
  bf16x2 o; o[0] = (bf16_t)a0; o[1] = (bf16_t)a1;
  *(bf16x2*)(m + (size_t)b * N_NODES * HDIM + (size_t)i * HDIM + c) = o;
}

__device__ inline float wred(float v) {
#pragma unroll
  for (int m = 32; m; m >>= 1) v += __shfl_xor(v, m);
  return v;
}

// h lives in out_h (f32, written by last conv GEMM). Computes node_health, ds, dd, pg partials.
__global__ __launch_bounds__(256) void node_out(const float* __restrict__ h,
                                                const float* __restrict__ Wcls,
                                                const float* __restrict__ bcls,
                                                const float* __restrict__ Wep,
                                                const float* __restrict__ Wgp,
                                                float* __restrict__ ds, float* __restrict__ dd,
                                                float* __restrict__ pg_part,
                                                float* __restrict__ out_nh) {
  int lane = threadIdx.x & 63;
  int gw = blockIdx.x * 4 + (threadIdx.x >> 6);  // 0..1023, 16 rows each
  int row0 = gw * 16;
  float wc[4][5], wsv[4], wdv[4], wgv[4];
#pragma unroll
  for (int j = 0; j < 4; ++j) {
    int k = 4 * lane + j;
#pragma unroll
    for (int c = 0; c < 5; ++c) wc[j][c] = Wcls[k * 5 + c];
    wsv[j] = Wep[k];
    wdv[j] = Wep[256 + k];
    wgv[j] = Wgp[k];
  }
  float bc[5];
#pragma unroll
  for (int c = 0; c < 5; ++c) bc[c] = bcls[c];
  float pg_acc = 0.f;
  for (int n = 0; n < 16; ++n) {
    int row = row0 + n;
    const float4 x = *(const float4*)(h + (size_t)row * HDIM + 4 * lane);
    float xs[4] = {x.x, x.y, x.z, x.w};
    float pc0 = 0, pc1 = 0, pc2 = 0, pc3 = 0, pc4 = 0, ps = 0, pd = 0, pg = 0;
#pragma unroll
    for (int j = 0; j < 4; ++j) {
      float xv = xs[j];
      pc0 += xv * wc[j][0]; pc1 += xv * wc[j][1]; pc2 += xv * wc[j][2];
      pc3 += xv * wc[j][3]; pc4 += xv * wc[j][4];
      ps += xv * wsv[j]; pd += xv * wdv[j]; pg += xv * wgv[j];
    }
    pg_acc += pg;
    pc0 = wred(pc0); pc1 = wred(pc1); pc2 = wred(pc2); pc3 = wred(pc3); pc4 = wred(pc4);
    ps = wred(ps); pd = wred(pd);
    if (lane == 0) {
      out_nh[(size_t)row * 5 + 0] = pc0 + bc[0];
      out_nh[(size_t)row * 5 + 1] = pc1 + bc[1];
      out_nh[(size_t)row * 5 + 2] = pc2 + bc[2];
      out_nh[(size_t)row * 5 + 3] = pc3 + bc[3];
      out_nh[(size_t)row * 5 + 4] = pc4 + bc[4];
      ds[row] = ps;
      dd[row] = pd;
    }
  }
  float g = wred(pg_acc);
  if (lane == 0) pg_part[gw] = g;
}

__global__ __launch_bounds__(256) void edge_out(const float* __restrict__ ds,
                                                const float* __restrict__ dd,
                                                const int* __restrict__ src,
                                                const int* __restrict__ dst,
                                                const float* __restrict__ bep,
                                                float* __restrict__ out_ep) {
  int t = blockIdx.x * blockDim.x + threadIdx.x;  // < 262144
  int b = t >> 17;
  int e = t & (N_EDGES - 1);
  float v = ds[(b << 13) + src[e]] + dd[(b << 13) + dst[e]] + bep[0];
  out_ep[t] = 1.f / (1.f + expf(-v));
}

__global__ void sys_out(const float* __restrict__ pg_part, const float* __restrict__ bgp,
                        float* __restrict__ out_sys) {
  int b = blockIdx.x, t = threadIdx.x;  // 256 threads
  float v = pg_part[b * 512 + t] + pg_part[b * 512 + 256 + t];
#pragma unroll
  for (int m = 32; m; m >>= 1) v += __shfl_xor(v, m);
  __shared__ float s[4];
  if ((t & 63) == 0) s[t >> 6] = v;
  __syncthreads();
  if (t == 0) {
    float tot = s[0] + s[1] + s[2] + s[3];
    float g = tot / (float)N_NODES + bgp[0];
    out_sys[b] = 1.f / (1.f + expf(-g));
  }
}

extern "C" void kernel_launch(void* const* d_in, const int* in_sizes, int n_in,
                              void* d_out, int out_size, void* d_ws, size_t ws_size,
                              hipStream_t stream) {
  (void)in_sizes; (void)n_in; (void)out_size;
  const float* nf    = (const float*)d_in[0];
  const int*   src   = (const int*)d_in[3];
  const int*   dst   = (const int*)d_in[4];
  const float* Wne   = (const float*)d_in[5];
  const float* bne   = (const float*)d_in[6];
  const float* Wconv = (const float*)d_in[9];
  const float* bconv = (const float*)d_in[10];
  const float* Wcls  = (const float*)d_in[11];
  const float* bcls  = (const float*)d_in[12];
  const float* Wep   = (const float*)d_in[13];
  const float* bep   = (const float*)d_in[14];
  const float* Wgp   = (const float*)d_in[15];
  const float* bgp   = (const float*)d_in[16];

  bool shadow = ws_size >= 34213888ull;
  char* ws = (char*)d_ws;
  float*  h_f32  = (float*)(ws + 0);
  bf16_t* m_bf16 = (bf16_t*)(ws + 16777216);
  bf16_t* h_bf16 = shadow ? (bf16_t*)(ws + 25165824) : nullptr;
  size_t tail = shadow ? 33554432 : 25165824;
  bf16_t* WneT   = (bf16_t*)(ws + tail);
  bf16_t* WconvT = (bf16_t*)(ws + tail + 65536);
  int*    rp     = (int*)(ws + tail + 458752);
  float*  ds     = (float*)(ws + tail + 524288);
  float*  dd     = (float*)(ws + tail + 589824);
  float*  pg     = (float*)(ws + tail + 655360);

  float* out     = (float*)d_out;
  float* out_nh  = out;            // 81920
  float* out_ep  = out + 81920;    // 262144
  float* out_sys = out + 344064;   // 2
  float* out_h   = out + 344066;   // 4194304  (f32 h master for the final layer)

  hipLaunchKernelGGL(rowptr_kernel, dim3(33), dim3(256), 0, stream, src, rp);
  hipLaunchKernelGGL(transpose_w, dim3(896), dim3(256), 0, stream, Wne, Wconv, WneT, WconvT);
  hipLaunchKernelGGL((gemm_relu<128, false, true>), dim3(256, 4), dim3(256), 0, stream,
                     nf, WneT, bne, h_f32, h_f32, h_bf16);
  for (int l = 0; l < 3; ++l) {
    if (shadow)
      hipLaunchKernelGGL(gather_b16, dim3(8192), dim3(256), 0, stream, h_bf16, rp, dst, m_bf16);
    else
      hipLaunchKernelGGL(gather_f32, dim3(8192), dim3(256), 0, stream, h_f32, rp, dst, m_bf16);
    float* hout = (l == 2) ? out_h : h_f32;
    bf16_t* s16 = (l == 2) ? nullptr : h_bf16;
    hipLaunchKernelGGL((gemm_relu<256, true, false>), dim3(256, 4), dim3(256), 0, stream,
                       m_bf16, WconvT + l * 65536, bconv + l * 256, h_f32, hout, s16);
  }
  hipLaunchKernelGGL(node_out, dim3(256), dim3(256), 0, stream, out_h, Wcls, bcls, Wep, Wgp,
                     ds, dd, pg, out_nh);
  hipLaunchKernelGGL(edge_out, dim3(1024), dim3(256), 0, stream, ds, dd, src, dst, bep, out_ep);
  hipLaunchKernelGGL(sys_out, dim3(2), dim3(256), 0, stream, pg, bgp, out_sys);
}

// Round 4
// 152.729 us; speedup vs baseline: 2.0630x; 1.2177x over previous
//
#include <hip/hip_runtime.h>
#include <hip/hip_bf16.h>

typedef __bf16 bf16_t;
typedef __bf16 bf16x2 __attribute__((ext_vector_type(2)));
typedef __bf16 bf16x8 __attribute__((ext_vector_type(8)));
typedef float f32x4 __attribute__((ext_vector_type(4)));

#define N_NODES 8192
#define N_EDGES 131072
#define BATCH   2
#define HDIM    256
#define M_ROWS  (BATCH * N_NODES)  // 16384

// ---- ws layout (bytes), shadow variant (needs 34,213,888 B) ----
// h_f32 : 0 (16,777,216) | m_bf16 : 16777216 (8,388,608) | h_bf16 : 25165824 (8,388,608)
// then WneT(65,536) WconvT(393,216) rp(32,772) ds(65,536) dd(65,536) pg(4,096)

__global__ __launch_bounds__(256) void rowptr_kernel(const int* __restrict__ src, int* __restrict__ rp) {
  int i = blockIdx.x * blockDim.x + threadIdx.x;
  if (i > N_NODES) return;
  if (i == N_NODES) { rp[i] = N_EDGES; return; }
  int lo = 0, hi = N_EDGES;
  while (lo < hi) { int mid = (lo + hi) >> 1; if (src[mid] < i) lo = mid + 1; else hi = mid; }
  rp[i] = lo;
}

__global__ __launch_bounds__(256) void transpose_w(const float* __restrict__ Wne,
                                                   const float* __restrict__ Wconv,
                                                   bf16_t* __restrict__ WneT,
                                                   bf16_t* __restrict__ WconvT) {
  int t = blockIdx.x * blockDim.x + threadIdx.x;
  if (t < 256 * 128) {
    int n = t / 128, k = t % 128;
    WneT[t] = (bf16_t)Wne[k * 256 + n];
  } else {
    int u = t - 256 * 128;
    if (u < 3 * 256 * 256) {
      int l = u / 65536, r = u % 65536;
      int n = r / 256, k = r % 256;
      WconvT[l * 65536 + n * 256 + k] = (bf16_t)Wconv[l * 65536 + k * 256 + n];
    }
  }
}

// batch -> XCD-half swizzle for 256-row-block grids: xcd = blockIdx&7; batch = xcd>>2.
__device__ inline int rowblk_swz(int x) {
  int xcd = x & 7, q = x >> 3;                 // q: 0..31
  return (xcd >> 2) * 128 + (xcd & 3) * 32 + q; // 0..255
}

// C = relu(A @ B + bias) [+ Hin]; writes f32 Hout and optional bf16 shadow S16.
// Grid (256, 4), block = 4 waves; wave = 1 row-tile x 4 col-tiles, A-frags cached.
template<int K, bool FUSE, bool AF32>
__global__ __launch_bounds__(256) void gemm_relu(const void* __restrict__ Av,
                                                 const bf16_t* __restrict__ BT,
                                                 const float* __restrict__ bias,
                                                 const float* __restrict__ Hin,
                                                 float* __restrict__ Hout,
                                                 bf16_t* __restrict__ S16) {
  constexpr int NK = K / 32;
  int lane = threadIdx.x & 63;
  int wv = threadIdx.x >> 6;
  int r0 = (rowblk_swz(blockIdx.x) * 4 + wv) * 16;
  int cg0 = blockIdx.y * 64;
  int l15 = lane & 15, l4 = lane >> 4;
  bf16x8 a[NK];
  if (AF32) {
    const float* Ap = (const float*)Av + (size_t)(r0 + l15) * K + 8 * l4;
#pragma unroll
    for (int kk = 0; kk < NK; ++kk) {
      f32x4 a0 = *(const f32x4*)(Ap + 32 * kk);
      f32x4 a1 = *(const f32x4*)(Ap + 32 * kk + 4);
#pragma unroll
      for (int j = 0; j < 4; ++j) { a[kk][j] = (bf16_t)a0[j]; a[kk][4 + j] = (bf16_t)a1[j]; }
    }
  } else {
    const bf16_t* Ap = (const bf16_t*)Av + (size_t)(r0 + l15) * K + 8 * l4;
#pragma unroll
    for (int kk = 0; kk < NK; ++kk) a[kk] = *(const bf16x8*)(Ap + 32 * kk);
  }
#pragma unroll
  for (int ct = 0; ct < 4; ++ct) {
    int c0 = cg0 + ct * 16;
    const bf16_t* Bp = BT + (size_t)(c0 + l15) * K + 8 * l4;
    f32x4 acc = {0.f, 0.f, 0.f, 0.f};
#pragma unroll
    for (int kk = 0; kk < NK; ++kk)
      acc = __builtin_amdgcn_mfma_f32_16x16x32_bf16(a[kk], *(const bf16x8*)(Bp + 32 * kk), acc, 0, 0, 0);
    int col = c0 + l15;
    float bv = bias[col];
#pragma unroll
    for (int i = 0; i < 4; ++i) {
      int row = r0 + 4 * l4 + i;
      size_t idx = (size_t)row * HDIM + col;
      float v = fmaxf(acc[i] + bv, 0.f);
      if (FUSE) v += Hin[idx];
      Hout[idx] = v;
      if (S16) S16[idx] = (bf16_t)v;
    }
  }
}

// m[b,i,:] = sum over edges src==i of h[b,dst[e],:]. 16B loads: 32 lanes x 8 cols per row.
// 8 rows/block, grid 2048, batch->XCD-half swizzle.
__global__ __launch_bounds__(256) void gather_b16(const bf16_t* __restrict__ h,
                                                  const int* __restrict__ rp,
                                                  const int* __restrict__ dst,
                                                  bf16_t* __restrict__ m) {
  int tid = threadIdx.x;
  int gang = tid >> 5, l32 = tid & 31;
  int x = blockIdx.x;
  int xcd = x & 7, q = x >> 3;                // q: 0..255
  int b = xcd >> 2;
  int grp = (xcd & 3) * 256 + q;              // 0..1023
  int i = grp * 8 + gang;
  const bf16_t* hb = h + (size_t)b * (N_NODES * HDIM) + l32 * 8;
  int e0 = rp[i], e1 = rp[i + 1];
  float acc[8] = {0.f, 0.f, 0.f, 0.f, 0.f, 0.f, 0.f, 0.f};
  int e = e0;
  for (; e + 4 <= e1; e += 4) {
    int j0 = dst[e], j1 = dst[e + 1], j2 = dst[e + 2], j3 = dst[e + 3];
    bf16x8 v0 = *(const bf16x8*)(hb + (size_t)j0 * HDIM);
    bf16x8 v1 = *(const bf16x8*)(hb + (size_t)j1 * HDIM);
    bf16x8 v2 = *(const bf16x8*)(hb + (size_t)j2 * HDIM);
    bf16x8 v3 = *(const bf16x8*)(hb + (size_t)j3 * HDIM);
#pragma unroll
    for (int jj = 0; jj < 8; ++jj)
      acc[jj] += (float)v0[jj] + (float)v1[jj] + (float)v2[jj] + (float)v3[jj];
  }
  for (; e < e1; ++e) {
    bf16x8 v = *(const bf16x8*)(hb + (size_t)dst[e] * HDIM);
#pragma unroll
    for (int jj = 0; jj < 8; ++jj) acc[jj] += (float)v[jj];
  }
  bf16x8 o;
#pragma unroll
  for (int jj = 0; jj < 8; ++jj) o[jj] = (bf16_t)acc[jj];
  *(bf16x8*)(m + (size_t)b * (N_NODES * HDIM) + (size_t)i * HDIM + l32 * 8) = o;
}

// fallback (no shadow): f32 source, 16B loads: 64 lanes x 4 cols; 4 rows/block, grid 4096.
__global__ __launch_bounds__(256) void gather_f32(const float* __restrict__ h,
                                                  const int* __restrict__ rp,
                                                  const int* __restrict__ dst,
                                                  bf16_t* __restrict__ m) {
  int tid = threadIdx.x;
  int gang = tid >> 6, l64 = tid & 63;
  int x = blockIdx.x;
  int xcd = x & 7, q = x >> 3;                // q: 0..511
  int b = xcd >> 2;
  int grp = (xcd & 3) * 512 + q;              // 0..2047
  int i = grp * 4 + gang;
  const float* hb = h + (size_t)b * (N_NODES * HDIM) + l64 * 4;
  int e0 = rp[i], e1 = rp[i + 1];
  float a0 = 0.f, a1 = 0.f, a2 = 0.f, a3 = 0.f;
  int e = e0;
  for (; e + 4 <= e1; e += 4) {
    int j0 = dst[e], j1 = dst[e + 1], j2 = dst[e + 2], j3 = dst[e + 3];
    f32x4 v0 = *(const f32x4*)(hb + (size_t)j0 * HDIM);
    f32x4 v1 = *(const f32x4*)(hb + (size_t)j1 * HDIM);
    f32x4 v2 = *(const f32x4*)(hb + (size_t)j2 * HDIM);
    f32x4 v3 = *(const f32x4*)(hb + (size_t)j3 * HDIM);
    a0 += v0[0] + v1[0] + v2[0] + v3[0];
    a1 += v0[1] + v1[1] + v2[1] + v3[1];
    a2 += v0[2] + v1[2] + v2[2] + v3[2];
    a3 += v0[3] + v1[3] + v2[3] + v3[3];
  }
  for (; e < e1; ++e) {
    f32x4 v = *(const f32x4*)(hb + (size_t)dst[e] * HDIM);
    a0 += v[0]; a1 += v[1]; a2 += v[2]; a3 += v[3];
  }
  bf16_t* mp = m + (size_t)b * (N_NODES * HDIM) + (size_t)i * HDIM + l64 * 4;
  bf16x2 o01, o23;
  o01[0] = (bf16_t)a0; o01[1] = (bf16_t)a1;
  o23[0] = (bf16_t)a2; o23[1] = (bf16_t)a3;
  *(bf16x2*)(mp) = o01;
  *(bf16x2*)(mp + 2) = o23;
}

__device__ inline float wred(float v) {
#pragma unroll
  for (int m = 32; m; m >>= 1) v += __shfl_xor(v, m);
  return v;
}

__global__ __launch_bounds__(256) void node_out(const float* __restrict__ h,
                                                const float* __restrict__ Wcls,
                                                const float* __restrict__ bcls,
                                                const float* __restrict__ Wep,
                                                const float* __restrict__ Wgp,
                                                float* __restrict__ ds, float* __restrict__ dd,
                                                float* __restrict__ pg_part,
                                                float* __restrict__ out_nh) {
  int lane = threadIdx.x & 63;
  int gw = blockIdx.x * 4 + (threadIdx.x >> 6);  // 0..1023, 16 rows each
  int row0 = gw * 16;
  float wc[4][5], wsv[4], wdv[4], wgv[4];
#pragma unroll
  for (int j = 0; j < 4; ++j) {
    int k = 4 * lane + j;
#pragma unroll
    for (int c = 0; c < 5; ++c) wc[j][c] = Wcls[k * 5 + c];
    wsv[j] = Wep[k];
    wdv[j] = Wep[256 + k];
    wgv[j] = Wgp[k];
  }
  float bc[5];
#pragma unroll
  for (int c = 0; c < 5; ++c) bc[c] = bcls[c];
  float pg_acc = 0.f;
  for (int n = 0; n < 16; ++n) {
    int row = row0 + n;
    const float4 x = *(const float4*)(h + (size_t)row * HDIM + 4 * lane);
    float xs[4] = {x.x, x.y, x.z, x.w};
    float pc0 = 0, pc1 = 0, pc2 = 0, pc3 = 0, pc4 = 0, ps = 0, pd = 0, pg = 0;
#pragma unroll
    for (int j = 0; j < 4; ++j) {
      float xv = xs[j];
      pc0 += xv * wc[j][0]; pc1 += xv * wc[j][1]; pc2 += xv * wc[j][2];
      pc3 += xv * wc[j][3]; pc4 += xv * wc[j][4];
      ps += xv * wsv[j]; pd += xv * wdv[j]; pg += xv * wgv[j];
    }
    pg_acc += pg;
    pc0 = wred(pc0); pc1 = wred(pc1); pc2 = wred(pc2); pc3 = wred(pc3); pc4 = wred(pc4);
    ps = wred(ps); pd = wred(pd);
    if (lane == 0) {
      out_nh[(size_t)row * 5 + 0] = pc0 + bc[0];
      out_nh[(size_t)row * 5 + 1] = pc1 + bc[1];
      out_nh[(size_t)row * 5 + 2] = pc2 + bc[2];
      out_nh[(size_t)row * 5 + 3] = pc3 + bc[3];
      out_nh[(size_t)row * 5 + 4] = pc4 + bc[4];
      ds[row] = ps;
      dd[row] = pd;
    }
  }
  float g = wred(pg_acc);
  if (lane == 0) pg_part[gw] = g;
}

__global__ __launch_bounds__(256) void edge_out(const float* __restrict__ ds,
                                                const float* __restrict__ dd,
                                                const int* __restrict__ src,
                                                const int* __restrict__ dst,
                                                const float* __restrict__ bep,
                                                float* __restrict__ out_ep) {
  int t = blockIdx.x * blockDim.x + threadIdx.x;  // < 262144
  int b = t >> 17;
  int e = t & (N_EDGES - 1);
  float v = ds[(b << 13) + src[e]] + dd[(b << 13) + dst[e]] + bep[0];
  out_ep[t] = 1.f / (1.f + expf(-v));
}

__global__ void sys_out(const float* __restrict__ pg_part, const float* __restrict__ bgp,
                        float* __restrict__ out_sys) {
  int b = blockIdx.x, t = threadIdx.x;  // 256 threads
  float v = pg_part[b * 512 + t] + pg_part[b * 512 + 256 + t];
#pragma unroll
  for (int m = 32; m; m >>= 1) v += __shfl_xor(v, m);
  __shared__ float s[4];
  if ((t & 63) == 0) s[t >> 6] = v;
  __syncthreads();
  if (t == 0) {
    float tot = s[0] + s[1] + s[2] + s[3];
    float g = tot / (float)N_NODES + bgp[0];
    out_sys[b] = 1.f / (1.f + expf(-g));
  }
}

extern "C" void kernel_launch(void* const* d_in, const int* in_sizes, int n_in,
                              void* d_out, int out_size, void* d_ws, size_t ws_size,
                              hipStream_t stream) {
  (void)in_sizes; (void)n_in; (void)out_size;
  const float* nf    = (const float*)d_in[0];
  const int*   src   = (const int*)d_in[3];
  const int*   dst   = (const int*)d_in[4];
  const float* Wne   = (const float*)d_in[5];
  const float* bne   = (const float*)d_in[6];
  const float* Wconv = (const float*)d_in[9];
  const float* bconv = (const float*)d_in[10];
  const float* Wcls  = (const float*)d_in[11];
  const float* bcls  = (const float*)d_in[12];
  const float* Wep   = (const float*)d_in[13];
  const float* bep   = (const float*)d_in[14];
  const float* Wgp   = (const float*)d_in[15];
  const float* bgp   = (const float*)d_in[16];

  bool shadow = ws_size >= 34213888ull;
  char* ws = (char*)d_ws;
  float*  h_f32  = (float*)(ws + 0);
  bf16_t* m_bf16 = (bf16_t*)(ws + 16777216);
  bf16_t* h_bf16 = shadow ? (bf16_t*)(ws + 25165824) : nullptr;
  size_t tail = shadow ? 33554432 : 25165824;
  bf16_t* WneT   = (bf16_t*)(ws + tail);
  bf16_t* WconvT = (bf16_t*)(ws + tail + 65536);
  int*    rp     = (int*)(ws + tail + 458752);
  float*  ds     = (float*)(ws + tail + 524288);
  float*  dd     = (float*)(ws + tail + 589824);
  float*  pg     = (float*)(ws + tail + 655360);

  float* out     = (float*)d_out;
  float* out_nh  = out;            // 81920
  float* out_ep  = out + 81920;    // 262144
  float* out_sys = out + 344064;   // 2
  float* out_h   = out + 344066;   // 4194304  (f32 h master for the final layer)

  hipLaunchKernelGGL(rowptr_kernel, dim3(33), dim3(256), 0, stream, src, rp);
  hipLaunchKernelGGL(transpose_w, dim3(896), dim3(256), 0, stream, Wne, Wconv, WneT, WconvT);
  hipLaunchKernelGGL((gemm_relu<128, false, true>), dim3(256, 4), dim3(256), 0, stream,
                     nf, WneT, bne, h_f32, h_f32, h_bf16);
  for (int l = 0; l < 3; ++l) {
    if (shadow)
      hipLaunchKernelGGL(gather_b16, dim3(2048), dim3(256), 0, stream, h_bf16, rp, dst, m_bf16);
    else
      hipLaunchKernelGGL(gather_f32, dim3(4096), dim3(256), 0, stream, h_f32, rp, dst, m_bf16);
    float* hout = (l == 2) ? out_h : h_f32;
    bf16_t* s16 = (l == 2) ? nullptr : h_bf16;
    hipLaunchKernelGGL((gemm_relu<256, true, false>), dim3(256, 4), dim3(256), 0, stream,
                       m_bf16, WconvT + l * 65536, bconv + l * 256, h_f32, hout, s16);
  }
  hipLaunchKernelGGL(node_out, dim3(256), dim3(256), 0, stream, out_h, Wcls, bcls, Wep, Wgp,
                     ds, dd, pg, out_nh);
  hipLaunchKernelGGL(edge_out, dim3(1024), dim3(256), 0, stream, ds, dd, src, dst, bep, out_ep);
  hipLaunchKernelGGL(sys_out, dim3(2), dim3(256), 0, stream, pg, bgp, out_sys);
}

// Round 5
// 139.359 us; speedup vs baseline: 2.2609x; 1.0959x over previous
//
#include <hip/hip_runtime.h>
#include <hip/hip_bf16.h>

typedef __bf16 bf16_t;
typedef __bf16 bf16x2 __attribute__((ext_vector_type(2)));
typedef __bf16 bf16x8 __attribute__((ext_vector_type(8)));
typedef float f32x4 __attribute__((ext_vector_type(4)));

#define N_NODES 8192
#define N_EDGES 131072
#define BATCH   2
#define HDIM    256
#define M_ROWS  (BATCH * N_NODES)  // 16384

// ---- ws layout (fused path, needs <= 34,213,888 B) ----
// h_f32 : 0 (16,777,216) | hs0 : 16777216 (8,388,608) | hs1 : 25165824 (8,388,608)
// tail @ 33554432: WneT(65,536) WconvT(393,216) rp(32,772) ds(65,536) dd(65,536) pg(4,096)
// fallback (no shadow): h_f32@0, m_bf16@16777216, tail@25165824.

// prep: blocks 0..32 = CSR row pointers (binary search); blocks 33.. = weight transpose->bf16.
__global__ __launch_bounds__(256) void prep(const int* __restrict__ src, int* __restrict__ rp,
                                            const float* __restrict__ Wne,
                                            const float* __restrict__ Wconv,
                                            bf16_t* __restrict__ WneT,
                                            bf16_t* __restrict__ WconvT) {
  int x = blockIdx.x, tid = threadIdx.x;
  if (x < 33) {
    int i = x * 256 + tid;
    if (i > N_NODES) return;
    if (i == N_NODES) { rp[i] = N_EDGES; return; }
    int lo = 0, hi = N_EDGES;
    while (lo < hi) { int mid = (lo + hi) >> 1; if (src[mid] < i) lo = mid + 1; else hi = mid; }
    rp[i] = lo;
  } else {
    int t = (x - 33) * 256 + tid;
    if (t < 256 * 128) {
      int n = t / 128, k = t % 128;
      WneT[t] = (bf16_t)Wne[k * 256 + n];
    } else {
      int u = t - 256 * 128;
      if (u < 3 * 256 * 256) {
        int l = u / 65536, r = u % 65536;
        int n = r / 256, k = r % 256;
        WconvT[l * 65536 + n * 256 + k] = (bf16_t)Wconv[l * 65536 + k * 256 + n];
      }
    }
  }
}

// batch -> XCD-half swizzle for 256-row-block grids.
__device__ inline int rowblk_swz(int x) {
  int xcd = x & 7, q = x >> 3;
  return (xcd >> 2) * 128 + (xcd & 3) * 32 + q;
}

// First layer: h = relu(nf @ Wne + bne). A fp32 -> bf16 in-register. Writes h_f32 + hs0 shadow.
template<int K>
__global__ __launch_bounds__(256) void gemm1(const float* __restrict__ A,
                                             const bf16_t* __restrict__ BT,
                                             const float* __restrict__ bias,
                                             float* __restrict__ Hout,
                                             bf16_t* __restrict__ S16) {
  constexpr int NK = K / 32;
  int lane = threadIdx.x & 63;
  int wv = threadIdx.x >> 6;
  int r0 = (rowblk_swz(blockIdx.x) * 4 + wv) * 16;
  int cg0 = blockIdx.y * 64;
  int l15 = lane & 15, l4 = lane >> 4;
  bf16x8 a[NK];
  const float* Ap = A + (size_t)(r0 + l15) * K + 8 * l4;
#pragma unroll
  for (int kk = 0; kk < NK; ++kk) {
    f32x4 a0 = *(const f32x4*)(Ap + 32 * kk);
    f32x4 a1 = *(const f32x4*)(Ap + 32 * kk + 4);
#pragma unroll
    for (int j = 0; j < 4; ++j) { a[kk][j] = (bf16_t)a0[j]; a[kk][4 + j] = (bf16_t)a1[j]; }
  }
#pragma unroll
  for (int ct = 0; ct < 4; ++ct) {
    int c0 = cg0 + ct * 16;
    const bf16_t* Bp = BT + (size_t)(c0 + l15) * K + 8 * l4;
    f32x4 acc = {0.f, 0.f, 0.f, 0.f};
#pragma unroll
    for (int kk = 0; kk < NK; ++kk)
      acc = __builtin_amdgcn_mfma_f32_16x16x32_bf16(a[kk], *(const bf16x8*)(Bp + 32 * kk), acc, 0, 0, 0);
    int col = c0 + l15;
    float bv = bias[col];
#pragma unroll
    for (int i = 0; i < 4; ++i) {
      int row = r0 + 4 * l4 + i;
      size_t idx = (size_t)row * HDIM + col;
      float v = fmaxf(acc[i] + bv, 0.f);
      Hout[idx] = v;
      if (S16) S16[idx] = (bf16_t)v;
    }
  }
}

// Fused gather + conv GEMM. Block = 16 rows x 256 cols, grid 1024.
// Gather: 8 gangs of 32 lanes sum h_in[dst] rows (bf16x8, 8-deep) into XOR-swizzled LDS.
// MFMA: 4 waves x 64 cols each; A-frags from LDS; relu+bias+residual epilogue.
// hs_out must differ from hs_in (cross-block race otherwise) -> ping-pong shadows.
template<bool LAST>
__global__ __launch_bounds__(256) void gconv(const bf16_t* __restrict__ hs_in,
                                             const int* __restrict__ rp,
                                             const int* __restrict__ dst,
                                             const bf16_t* __restrict__ BT,
                                             const float* __restrict__ bias,
                                             float* __restrict__ Hio,
                                             float* __restrict__ Hlast,
                                             bf16_t* __restrict__ hs_out) {
  __shared__ bf16_t A_lds[16 * 256];  // 8 KB, 16B-granule XOR swizzle: g ^= (row & 7)
  int tid = threadIdx.x;
  int x = blockIdx.x;
  int xcd = x & 7, q = x >> 3;            // q: 0..127
  int b = xcd >> 2;
  int blk = (xcd & 3) * 128 + q;          // 0..511 within batch
  int i0 = blk * 16;
  int gang = tid >> 5, l32 = tid & 31;
  const bf16_t* hb = hs_in + (size_t)b * (N_NODES * HDIM) + l32 * 8;
#pragma unroll
  for (int r2 = 0; r2 < 2; ++r2) {
    int lrow = gang * 2 + r2;
    int i = i0 + lrow;
    int e0 = rp[i], e1 = rp[i + 1];
    float acc[8] = {0.f, 0.f, 0.f, 0.f, 0.f, 0.f, 0.f, 0.f};
    int e = e0;
    for (; e + 8 <= e1; e += 8) {
      bf16x8 v[8];
#pragma unroll
      for (int u = 0; u < 8; ++u) v[u] = *(const bf16x8*)(hb + (size_t)dst[e + u] * HDIM);
#pragma unroll
      for (int u = 0; u < 8; ++u)
#pragma unroll
        for (int jj = 0; jj < 8; ++jj) acc[jj] += (float)v[u][jj];
    }
    for (; e < e1; ++e) {
      bf16x8 v = *(const bf16x8*)(hb + (size_t)dst[e] * HDIM);
#pragma unroll
      for (int jj = 0; jj < 8; ++jj) acc[jj] += (float)v[jj];
    }
    bf16x8 o;
#pragma unroll
    for (int jj = 0; jj < 8; ++jj) o[jj] = (bf16_t)acc[jj];
    *(bf16x8*)&A_lds[lrow * 256 + ((l32 ^ (lrow & 7)) * 8)] = o;
  }
  __syncthreads();
  int lane = tid & 63, wv = tid >> 6;
  int l15 = lane & 15, l4 = lane >> 4;
  bf16x8 a[8];
#pragma unroll
  for (int kk = 0; kk < 8; ++kk)
    a[kk] = *(const bf16x8*)&A_lds[l15 * 256 + (((kk * 4 + l4) ^ (l15 & 7)) * 8)];
  int row_base = b * N_NODES + i0;
#pragma unroll
  for (int ct = 0; ct < 4; ++ct) {
    int c0 = wv * 64 + ct * 16;
    const bf16_t* Bp = BT + (size_t)(c0 + l15) * HDIM + 8 * l4;
    f32x4 acc = {0.f, 0.f, 0.f, 0.f};
#pragma unroll
    for (int kk = 0; kk < 8; ++kk)
      acc = __builtin_amdgcn_mfma_f32_16x16x32_bf16(a[kk], *(const bf16x8*)(Bp + 32 * kk), acc, 0, 0, 0);
    int col = c0 + l15;
    float bv = bias[col];
#pragma unroll
    for (int ii = 0; ii < 4; ++ii) {
      int row = row_base + 4 * l4 + ii;
      size_t idx = (size_t)row * HDIM + col;
      float v = fmaxf(acc[ii] + bv, 0.f) + Hio[idx];
      if (LAST) {
        Hlast[idx] = v;
      } else {
        Hio[idx] = v;
        hs_out[idx] = (bf16_t)v;
      }
    }
  }
}

// ---------- fallback (no shadow space): round-3 style ----------
template<int K, bool FUSE, bool AF32>
__global__ __launch_bounds__(256) void gemm_relu(const void* __restrict__ Av,
                                                 const bf16_t* __restrict__ BT,
                                                 const float* __restrict__ bias,
                                                 const float* __restrict__ Hin,
                                                 float* __restrict__ Hout,
                                                 bf16_t* __restrict__ S16) {
  constexpr int NK = K / 32;
  int lane = threadIdx.x & 63;
  int wv = threadIdx.x >> 6;
  int r0 = (rowblk_swz(blockIdx.x) * 4 + wv) * 16;
  int cg0 = blockIdx.y * 64;
  int l15 = lane & 15, l4 = lane >> 4;
  bf16x8 a[NK];
  if (AF32) {
    const float* Ap = (const float*)Av + (size_t)(r0 + l15) * K + 8 * l4;
#pragma unroll
    for (int kk = 0; kk < NK; ++kk) {
      f32x4 a0 = *(const f32x4*)(Ap + 32 * kk);
      f32x4 a1 = *(const f32x4*)(Ap + 32 * kk + 4);
#pragma unroll
      for (int j = 0; j < 4; ++j) { a[kk][j] = (bf16_t)a0[j]; a[kk][4 + j] = (bf16_t)a1[j]; }
    }
  } else {
    const bf16_t* Ap = (const bf16_t*)Av + (size_t)(r0 + l15) * K + 8 * l4;
#pragma unroll
    for (int kk = 0; kk < NK; ++kk) a[kk] = *(const bf16x8*)(Ap + 32 * kk);
  }
#pragma unroll
  for (int ct = 0; ct < 4; ++ct) {
    int c0 = cg0 + ct * 16;
    const bf16_t* Bp = BT + (size_t)(c0 + l15) * K + 8 * l4;
    f32x4 acc = {0.f, 0.f, 0.f, 0.f};
#pragma unroll
    for (int kk = 0; kk < NK; ++kk)
      acc = __builtin_amdgcn_mfma_f32_16x16x32_bf16(a[kk], *(const bf16x8*)(Bp + 32 * kk), acc, 0, 0, 0);
    int col = c0 + l15;
    float bv = bias[col];
#pragma unroll
    for (int i = 0; i < 4; ++i) {
      int row = r0 + 4 * l4 + i;
      size_t idx = (size_t)row * HDIM + col;
      float v = fmaxf(acc[i] + bv, 0.f);
      if (FUSE) v += Hin[idx];
      Hout[idx] = v;
      if (S16) S16[idx] = (bf16_t)v;
    }
  }
}

__global__ __launch_bounds__(256) void gather_f32(const float* __restrict__ h,
                                                  const int* __restrict__ rp,
                                                  const int* __restrict__ dst,
                                                  bf16_t* __restrict__ m) {
  int tid = threadIdx.x;
  int gang = tid >> 6, l64 = tid & 63;
  int x = blockIdx.x;
  int xcd = x & 7, q = x >> 3;
  int b = xcd >> 2;
  int grp = (xcd & 3) * 512 + q;
  int i = grp * 4 + gang;
  const float* hb = h + (size_t)b * (N_NODES * HDIM) + l64 * 4;
  int e0 = rp[i], e1 = rp[i + 1];
  float a0 = 0.f, a1 = 0.f, a2 = 0.f, a3 = 0.f;
  int e = e0;
  for (; e + 4 <= e1; e += 4) {
    int j0 = dst[e], j1 = dst[e + 1], j2 = dst[e + 2], j3 = dst[e + 3];
    f32x4 v0 = *(const f32x4*)(hb + (size_t)j0 * HDIM);
    f32x4 v1 = *(const f32x4*)(hb + (size_t)j1 * HDIM);
    f32x4 v2 = *(const f32x4*)(hb + (size_t)j2 * HDIM);
    f32x4 v3 = *(const f32x4*)(hb + (size_t)j3 * HDIM);
    a0 += v0[0] + v1[0] + v2[0] + v3[0];
    a1 += v0[1] + v1[1] + v2[1] + v3[1];
    a2 += v0[2] + v1[2] + v2[2] + v3[2];
    a3 += v0[3] + v1[3] + v2[3] + v3[3];
  }
  for (; e < e1; ++e) {
    f32x4 v = *(const f32x4*)(hb + (size_t)dst[e] * HDIM);
    a0 += v[0]; a1 += v[1]; a2 += v[2]; a3 += v[3];
  }
  bf16_t* mp = m + (size_t)b * (N_NODES * HDIM) + (size_t)i * HDIM + l64 * 4;
  bf16x2 o01, o23;
  o01[0] = (bf16_t)a0; o01[1] = (bf16_t)a1;
  o23[0] = (bf16_t)a2; o23[1] = (bf16_t)a3;
  *(bf16x2*)(mp) = o01;
  *(bf16x2*)(mp + 2) = o23;
}
// ---------- end fallback ----------

__device__ inline float wred(float v) {
#pragma unroll
  for (int m = 32; m; m >>= 1) v += __shfl_xor(v, m);
  return v;
}

__global__ __launch_bounds__(256) void node_out(const float* __restrict__ h,
                                                const float* __restrict__ Wcls,
                                                const float* __restrict__ bcls,
                                                const float* __restrict__ Wep,
                                                const float* __restrict__ Wgp,
                                                float* __restrict__ ds, float* __restrict__ dd,
                                                float* __restrict__ pg_part,
                                                float* __restrict__ out_nh) {
  int lane = threadIdx.x & 63;
  int gw = blockIdx.x * 4 + (threadIdx.x >> 6);
  int row0 = gw * 16;
  float wc[4][5], wsv[4], wdv[4], wgv[4];
#pragma unroll
  for (int j = 0; j < 4; ++j) {
    int k = 4 * lane + j;
#pragma unroll
    for (int c = 0; c < 5; ++c) wc[j][c] = Wcls[k * 5 + c];
    wsv[j] = Wep[k];
    wdv[j] = Wep[256 + k];
    wgv[j] = Wgp[k];
  }
  float bc[5];
#pragma unroll
  for (int c = 0; c < 5; ++c) bc[c] = bcls[c];
  float pg_acc = 0.f;
  for (int n = 0; n < 16; ++n) {
    int row = row0 + n;
    const float4 x = *(const float4*)(h + (size_t)row * HDIM + 4 * lane);
    float xs[4] = {x.x, x.y, x.z, x.w};
    float pc0 = 0, pc1 = 0, pc2 = 0, pc3 = 0, pc4 = 0, ps = 0, pd = 0, pg = 0;
#pragma unroll
    for (int j = 0; j < 4; ++j) {
      float xv = xs[j];
      pc0 += xv * wc[j][0]; pc1 += xv * wc[j][1]; pc2 += xv * wc[j][2];
      pc3 += xv * wc[j][3]; pc4 += xv * wc[j][4];
      ps += xv * wsv[j]; pd += xv * wdv[j]; pg += xv * wgv[j];
    }
    pg_acc += pg;
    pc0 = wred(pc0); pc1 = wred(pc1); pc2 = wred(pc2); pc3 = wred(pc3); pc4 = wred(pc4);
    ps = wred(ps); pd = wred(pd);
    if (lane == 0) {
      out_nh[(size_t)row * 5 + 0] = pc0 + bc[0];
      out_nh[(size_t)row * 5 + 1] = pc1 + bc[1];
      out_nh[(size_t)row * 5 + 2] = pc2 + bc[2];
      out_nh[(size_t)row * 5 + 3] = pc3 + bc[3];
      out_nh[(size_t)row * 5 + 4] = pc4 + bc[4];
      ds[row] = ps;
      dd[row] = pd;
    }
  }
  float g = wred(pg_acc);
  if (lane == 0) pg_part[gw] = g;
}

// blocks 0..1023: edge sigmoid; blocks 1024..1025: system health reduce.
__global__ __launch_bounds__(256) void edge_sys(const float* __restrict__ ds,
                                                const float* __restrict__ dd,
                                                const int* __restrict__ src,
                                                const int* __restrict__ dst,
                                                const float* __restrict__ bep,
                                                const float* __restrict__ pg_part,
                                                const float* __restrict__ bgp,
                                                float* __restrict__ out_ep,
                                                float* __restrict__ out_sys) {
  int x = blockIdx.x;
  if (x < 1024) {
    int t = x * 256 + threadIdx.x;
    int b = t >> 17;
    int e = t & (N_EDGES - 1);
    float v = ds[(b << 13) + src[e]] + dd[(b << 13) + dst[e]] + bep[0];
    out_ep[t] = 1.f / (1.f + expf(-v));
  } else {
    int b = x - 1024, t = threadIdx.x;
    float v = pg_part[b * 512 + t] + pg_part[b * 512 + 256 + t];
#pragma unroll
    for (int m = 32; m; m >>= 1) v += __shfl_xor(v, m);
    __shared__ float s[4];
    if ((t & 63) == 0) s[t >> 6] = v;
    __syncthreads();
    if (t == 0) {
      float tot = s[0] + s[1] + s[2] + s[3];
      float g = tot / (float)N_NODES + bgp[0];
      out_sys[b] = 1.f / (1.f + expf(-g));
    }
  }
}

extern "C" void kernel_launch(void* const* d_in, const int* in_sizes, int n_in,
                              void* d_out, int out_size, void* d_ws, size_t ws_size,
                              hipStream_t stream) {
  (void)in_sizes; (void)n_in; (void)out_size;
  const float* nf    = (const float*)d_in[0];
  const int*   src   = (const int*)d_in[3];
  const int*   dst   = (const int*)d_in[4];
  const float* Wne   = (const float*)d_in[5];
  const float* bne   = (const float*)d_in[6];
  const float* Wconv = (const float*)d_in[9];
  const float* bconv = (const float*)d_in[10];
  const float* Wcls  = (const float*)d_in[11];
  const float* bcls  = (const float*)d_in[12];
  const float* Wep   = (const float*)d_in[13];
  const float* bep   = (const float*)d_in[14];
  const float* Wgp   = (const float*)d_in[15];
  const float* bgp   = (const float*)d_in[16];

  bool fused = ws_size >= 34213888ull;
  char* ws = (char*)d_ws;
  float*  h_f32 = (float*)(ws + 0);
  bf16_t* hs0   = (bf16_t*)(ws + 16777216);           // fused: shadow ping
  bf16_t* hs1   = (bf16_t*)(ws + 25165824);           // fused: shadow pong
  bf16_t* m_b16 = (bf16_t*)(ws + 16777216);           // fallback: gathered m
  size_t tail = fused ? 33554432 : 25165824;
  bf16_t* WneT   = (bf16_t*)(ws + tail);
  bf16_t* WconvT = (bf16_t*)(ws + tail + 65536);
  int*    rp     = (int*)(ws + tail + 458752);
  float*  ds     = (float*)(ws + tail + 524288);
  float*  dd     = (float*)(ws + tail + 589824);
  float*  pg     = (float*)(ws + tail + 655360);

  float* out     = (float*)d_out;
  float* out_nh  = out;            // 81920
  float* out_ep  = out + 81920;    // 262144
  float* out_sys = out + 344064;   // 2
  float* out_h   = out + 344066;   // 4194304 (f32 h master after last layer)

  hipLaunchKernelGGL(prep, dim3(929), dim3(256), 0, stream, src, rp, Wne, Wconv, WneT, WconvT);
  if (fused) {
    hipLaunchKernelGGL((gemm1<128>), dim3(256, 4), dim3(256), 0, stream, nf, WneT, bne, h_f32, hs0);
    hipLaunchKernelGGL((gconv<false>), dim3(1024), dim3(256), 0, stream,
                       hs0, rp, dst, WconvT + 0 * 65536, bconv + 0 * 256, h_f32, nullptr, hs1);
    hipLaunchKernelGGL((gconv<false>), dim3(1024), dim3(256), 0, stream,
                       hs1, rp, dst, WconvT + 1 * 65536, bconv + 1 * 256, h_f32, nullptr, hs0);
    hipLaunchKernelGGL((gconv<true>), dim3(1024), dim3(256), 0, stream,
                       hs0, rp, dst, WconvT + 2 * 65536, bconv + 2 * 256, h_f32, out_h, nullptr);
  } else {
    hipLaunchKernelGGL((gemm_relu<128, false, true>), dim3(256, 4), dim3(256), 0, stream,
                       nf, WneT, bne, h_f32, h_f32, nullptr);
    for (int l = 0; l < 3; ++l) {
      hipLaunchKernelGGL(gather_f32, dim3(4096), dim3(256), 0, stream, h_f32, rp, dst, m_b16);
      float* hout = (l == 2) ? out_h : h_f32;
      hipLaunchKernelGGL((gemm_relu<256, true, false>), dim3(256, 4), dim3(256), 0, stream,
                         m_b16, WconvT + l * 65536, bconv + l * 256, h_f32, hout, nullptr);
    }
  }
  hipLaunchKernelGGL(node_out, dim3(256), dim3(256), 0, stream, out_h, Wcls, bcls, Wep, Wgp,
                     ds, dd, pg, out_nh);
  hipLaunchKernelGGL(edge_sys, dim3(1026), dim3(256), 0, stream, ds, dd, src, dst, bep,
                     pg, bgp, out_ep, out_sys);
}

// Round 7
// 127.534 us; speedup vs baseline: 2.4706x; 1.0927x over previous
//
#include <hip/hip_runtime.h>
#include <hip/hip_bf16.h>

typedef __bf16 bf16_t;
typedef __bf16 bf16x8 __attribute__((ext_vector_type(8)));
typedef float f32x4 __attribute__((ext_vector_type(4)));

#define N_NODES 8192
#define N_EDGES 131072
#define HDIM    256

// ---- ws layout ----
// h_f32 : 0 (16,777,216) | hs0 : 16777216 (8,388,608) | hs1 : 25165824 (8,388,608)
// tail @ 33554432: WneT(65,536) WconvT(393,216) rp(32,772) ds(65,536) dd(65,536) pg(4,096)

__device__ inline int rowblk_swz(int x) {
  int xcd = x & 7, q = x >> 3;
  return (xcd >> 2) * 128 + (xcd & 3) * 32 + q;
}

__device__ inline float wred(float v) {
#pragma unroll
  for (int m = 32; m; m >>= 1) v += __shfl_xor(v, m);
  return v;
}

// prep: blocks 0..32 = CSR row pointers; 33..928 = weight transpose -> bf16.
__global__ __launch_bounds__(256) void prep_k(const int* __restrict__ src, int* __restrict__ rp,
                                              const float* __restrict__ Wne,
                                              const float* __restrict__ Wconv,
                                              bf16_t* __restrict__ WneT,
                                              bf16_t* __restrict__ WconvT) {
  int x = blockIdx.x, tid = threadIdx.x;
  if (x < 33) {
    int i = x * 256 + tid;
    if (i < N_NODES) {
      int lo = 0, hi = N_EDGES;
      while (lo < hi) { int mid = (lo + hi) >> 1; if (src[mid] < i) lo = mid + 1; else hi = mid; }
      rp[i] = lo;
    } else if (i == N_NODES) {
      rp[i] = N_EDGES;
    }
  } else {
    int t = (x - 33) * 256 + tid;
    if (t < 32768) {
      int n = t / 128, k = t % 128;
      WneT[t] = (bf16_t)Wne[k * 256 + n];
    } else {
      int u = t - 32768;
      int l = u / 65536, r = u % 65536;
      int n = r / 256, k = r % 256;
      WconvT[l * 65536 + n * 256 + k] = (bf16_t)Wconv[l * 65536 + k * 256 + n];
    }
  }
}

// h = relu(nf @ Wne + bne); f32 master + bf16 shadow. Grid (256,4).
__global__ __launch_bounds__(256) void gemm1_k(const float* __restrict__ A,
                                               const bf16_t* __restrict__ BT,
                                               const float* __restrict__ bias,
                                               float* __restrict__ Hout,
                                               bf16_t* __restrict__ S16) {
  int tid = threadIdx.x;
  int lane = tid & 63, wv = tid >> 6;
  int r0 = (rowblk_swz(blockIdx.x) * 4 + wv) * 16;
  int cg0 = blockIdx.y * 64;
  int l15 = lane & 15, l4 = lane >> 4;
  bf16x8 a[4];
  const float* Ap = A + (size_t)(r0 + l15) * 128 + 8 * l4;
#pragma unroll
  for (int kk = 0; kk < 4; ++kk) {
    f32x4 a0 = *(const f32x4*)(Ap + 32 * kk);
    f32x4 a1 = *(const f32x4*)(Ap + 32 * kk + 4);
#pragma unroll
    for (int j = 0; j < 4; ++j) { a[kk][j] = (bf16_t)a0[j]; a[kk][4 + j] = (bf16_t)a1[j]; }
  }
#pragma unroll
  for (int ct = 0; ct < 4; ++ct) {
    int c0 = cg0 + ct * 16;
    const bf16_t* Bp = BT + (size_t)(c0 + l15) * 128 + 8 * l4;
    f32x4 acc = {0.f, 0.f, 0.f, 0.f};
#pragma unroll
    for (int kk = 0; kk < 4; ++kk)
      acc = __builtin_amdgcn_mfma_f32_16x16x32_bf16(a[kk], *(const bf16x8*)(Bp + 32 * kk), acc, 0, 0, 0);
    int col = c0 + l15;
    float bv = bias[col];
#pragma unroll
    for (int i = 0; i < 4; ++i) {
      int row = r0 + 4 * l4 + i;
      size_t idx = (size_t)row * HDIM + col;
      float v = fmaxf(acc[i] + bv, 0.f);
      Hout[idx] = v;
      S16[idx] = (bf16_t)v;
    }
  }
}

// Fused gather + conv GEMM, middle layers. 16 rows/block, grid 1024.
__global__ __launch_bounds__(256) void gconv_k(const bf16_t* __restrict__ hs_in,
                                               const int* __restrict__ rp,
                                               const int* __restrict__ dst,
                                               const bf16_t* __restrict__ BT,
                                               const float* __restrict__ bias,
                                               float* __restrict__ Hio,
                                               bf16_t* __restrict__ hs_out) {
  __shared__ bf16_t A_lds[16 * 256];
  int tid = threadIdx.x;
  int x = blockIdx.x;
  int xcd = x & 7, q = x >> 3;
  int b = xcd >> 2;
  int blk = (xcd & 3) * 128 + q;
  int i0 = blk * 16;
  int gang = tid >> 5, l32 = tid & 31;
  const bf16_t* hb = hs_in + (size_t)b * (N_NODES * HDIM) + l32 * 8;
#pragma unroll
  for (int r2 = 0; r2 < 2; ++r2) {
    int lrow = gang * 2 + r2;
    int i = i0 + lrow;
    int e0 = rp[i], e1 = rp[i + 1];
    float acc[8] = {0.f, 0.f, 0.f, 0.f, 0.f, 0.f, 0.f, 0.f};
    int e = e0;
    for (; e + 8 <= e1; e += 8) {
      bf16x8 v[8];
#pragma unroll
      for (int u = 0; u < 8; ++u) v[u] = *(const bf16x8*)(hb + (size_t)dst[e + u] * HDIM);
#pragma unroll
      for (int u = 0; u < 8; ++u)
#pragma unroll
        for (int jj = 0; jj < 8; ++jj) acc[jj] += (float)v[u][jj];
    }
    for (; e < e1; ++e) {
      bf16x8 v = *(const bf16x8*)(hb + (size_t)dst[e] * HDIM);
#pragma unroll
      for (int jj = 0; jj < 8; ++jj) acc[jj] += (float)v[jj];
    }
    bf16x8 o;
#pragma unroll
    for (int jj = 0; jj < 8; ++jj) o[jj] = (bf16_t)acc[jj];
    *(bf16x8*)&A_lds[lrow * 256 + ((l32 ^ (lrow & 7)) * 8)] = o;
  }
  __syncthreads();
  int lane = tid & 63, wv = tid >> 6;
  int l15 = lane & 15, l4 = lane >> 4;
  bf16x8 a[8];
#pragma unroll
  for (int kk = 0; kk < 8; ++kk)
    a[kk] = *(const bf16x8*)&A_lds[l15 * 256 + (((kk * 4 + l4) ^ (l15 & 7)) * 8)];
  int row_base = b * N_NODES + i0;
#pragma unroll
  for (int ct = 0; ct < 4; ++ct) {
    int c0 = wv * 64 + ct * 16;
    const bf16_t* Bp = BT + (size_t)(c0 + l15) * HDIM + 8 * l4;
    f32x4 acc = {0.f, 0.f, 0.f, 0.f};
#pragma unroll
    for (int kk = 0; kk < 8; ++kk)
      acc = __builtin_amdgcn_mfma_f32_16x16x32_bf16(a[kk], *(const bf16x8*)(Bp + 32 * kk), acc, 0, 0, 0);
    int col = c0 + l15;
    float bv = bias[col];
#pragma unroll
    for (int ii = 0; ii < 4; ++ii) {
      int row = row_base + 4 * l4 + ii;
      size_t idx = (size_t)row * HDIM + col;
      float v = fmaxf(acc[ii] + bv, 0.f) + Hio[idx];
      Hio[idx] = v;
      hs_out[idx] = (bf16_t)v;
    }
  }
}

// Last layer: gconv + fused node heads (node_health, ds, dd, pg partial). Writes out_h f32.
__global__ __launch_bounds__(256) void gconv_heads_k(const bf16_t* __restrict__ hs_in,
                                                     const int* __restrict__ rp,
                                                     const int* __restrict__ dst,
                                                     const bf16_t* __restrict__ BT,
                                                     const float* __restrict__ bias,
                                                     const float* __restrict__ Hio,
                                                     float* __restrict__ out_h,
                                                     const float* __restrict__ Wcls,
                                                     const float* __restrict__ bcls,
                                                     const float* __restrict__ Wep,
                                                     const float* __restrict__ Wgp,
                                                     float* __restrict__ ds,
                                                     float* __restrict__ dd,
                                                     float* __restrict__ pg,
                                                     float* __restrict__ out_nh) {
  __shared__ bf16_t A_lds[16 * 256];
  __shared__ float red[4][16][8];
  __shared__ float pgrow[16];
  int tid = threadIdx.x;
  int x = blockIdx.x;
  int xcd = x & 7, q = x >> 3;
  int b = xcd >> 2;
  int blk = (xcd & 3) * 128 + q;
  int i0 = blk * 16;
  int gang = tid >> 5, l32 = tid & 31;
  const bf16_t* hb = hs_in + (size_t)b * (N_NODES * HDIM) + l32 * 8;
#pragma unroll
  for (int r2 = 0; r2 < 2; ++r2) {
    int lrow = gang * 2 + r2;
    int i = i0 + lrow;
    int e0 = rp[i], e1 = rp[i + 1];
    float acc[8] = {0.f, 0.f, 0.f, 0.f, 0.f, 0.f, 0.f, 0.f};
    int e = e0;
    for (; e + 8 <= e1; e += 8) {
      bf16x8 v[8];
#pragma unroll
      for (int u = 0; u < 8; ++u) v[u] = *(const bf16x8*)(hb + (size_t)dst[e + u] * HDIM);
#pragma unroll
      for (int u = 0; u < 8; ++u)
#pragma unroll
        for (int jj = 0; jj < 8; ++jj) acc[jj] += (float)v[u][jj];
    }
    for (; e < e1; ++e) {
      bf16x8 v = *(const bf16x8*)(hb + (size_t)dst[e] * HDIM);
#pragma unroll
      for (int jj = 0; jj < 8; ++jj) acc[jj] += (float)v[jj];
    }
    bf16x8 o;
#pragma unroll
    for (int jj = 0; jj < 8; ++jj) o[jj] = (bf16_t)acc[jj];
    *(bf16x8*)&A_lds[lrow * 256 + ((l32 ^ (lrow & 7)) * 8)] = o;
  }
  __syncthreads();
  int lane = tid & 63, wv = tid >> 6;
  int l15 = lane & 15, l4 = lane >> 4;
  bf16x8 a[8];
#pragma unroll
  for (int kk = 0; kk < 8; ++kk)
    a[kk] = *(const bf16x8*)&A_lds[l15 * 256 + (((kk * 4 + l4) ^ (l15 & 7)) * 8)];
  int row_base = b * N_NODES + i0;
  float p[4][8];
#pragma unroll
  for (int ii = 0; ii < 4; ++ii)
#pragma unroll
    for (int hh = 0; hh < 8; ++hh) p[ii][hh] = 0.f;
#pragma unroll
  for (int ct = 0; ct < 4; ++ct) {
    int c0 = wv * 64 + ct * 16;
    const bf16_t* Bp = BT + (size_t)(c0 + l15) * HDIM + 8 * l4;
    f32x4 acc = {0.f, 0.f, 0.f, 0.f};
#pragma unroll
    for (int kk = 0; kk < 8; ++kk)
      acc = __builtin_amdgcn_mfma_f32_16x16x32_bf16(a[kk], *(const bf16x8*)(Bp + 32 * kk), acc, 0, 0, 0);
    int col = c0 + l15;
    float bv = bias[col];
    float wc0 = Wcls[col * 5 + 0], wc1 = Wcls[col * 5 + 1], wc2 = Wcls[col * 5 + 2];
    float wc3 = Wcls[col * 5 + 3], wc4 = Wcls[col * 5 + 4];
    float wes = Wep[col], wed = Wep[256 + col], wgv = Wgp[col];
#pragma unroll
    for (int ii = 0; ii < 4; ++ii) {
      int row = row_base + 4 * l4 + ii;
      size_t idx = (size_t)row * HDIM + col;
      float v = fmaxf(acc[ii] + bv, 0.f) + Hio[idx];
      out_h[idx] = v;
      p[ii][0] += v * wc0; p[ii][1] += v * wc1; p[ii][2] += v * wc2;
      p[ii][3] += v * wc3; p[ii][4] += v * wc4;
      p[ii][5] += v * wes; p[ii][6] += v * wed; p[ii][7] += v * wgv;
    }
  }
  // reduce across the 16 l15-lanes (same rows)
#pragma unroll
  for (int ii = 0; ii < 4; ++ii)
#pragma unroll
    for (int hh = 0; hh < 8; ++hh) {
      float v = p[ii][hh];
#pragma unroll
      for (int m = 8; m; m >>= 1) v += __shfl_xor(v, m);
      p[ii][hh] = v;
    }
  if (l15 == 0) {
#pragma unroll
    for (int ii = 0; ii < 4; ++ii)
#pragma unroll
      for (int hh = 0; hh < 8; ++hh) red[wv][4 * l4 + ii][hh] = p[ii][hh];
  }
  __syncthreads();
  if (tid < 128) {
    int rl = tid >> 3, hh = tid & 7;
    float s = red[0][rl][hh] + red[1][rl][hh] + red[2][rl][hh] + red[3][rl][hh];
    int grow = row_base + rl;
    if (hh < 5)      out_nh[(size_t)grow * 5 + hh] = s + bcls[hh];
    else if (hh == 5) ds[grow] = s;
    else if (hh == 6) dd[grow] = s;
    else              pgrow[rl] = s;
  }
  __syncthreads();
  if (tid == 0) {
    float t = 0.f;
#pragma unroll
    for (int rl = 0; rl < 16; ++rl) t += pgrow[rl];
    pg[b * 512 + blk] = t;
  }
}

// blocks 0..1023: edge sigmoid; 1024..1025: system health.
__global__ __launch_bounds__(256) void edge_sys_k(const float* __restrict__ ds,
                                                  const float* __restrict__ dd,
                                                  const int* __restrict__ src,
                                                  const int* __restrict__ dst,
                                                  const float* __restrict__ bep,
                                                  const float* __restrict__ pg,
                                                  const float* __restrict__ bgp,
                                                  float* __restrict__ out_ep,
                                                  float* __restrict__ out_sys) {
  int x = blockIdx.x;
  if (x < 1024) {
    int t = x * 256 + threadIdx.x;
    int b = t >> 17;
    int e = t & (N_EDGES - 1);
    float v = ds[(b << 13) + src[e]] + dd[(b << 13) + dst[e]] + bep[0];
    out_ep[t] = 1.f / (1.f + expf(-v));
  } else {
    int b = x - 1024, t = threadIdx.x;
    float v = pg[b * 512 + t] + pg[b * 512 + 256 + t];
    v = wred(v);
    __shared__ float sm[4];
    if ((t & 63) == 0) sm[t >> 6] = v;
    __syncthreads();
    if (t == 0) {
      float tot = sm[0] + sm[1] + sm[2] + sm[3];
      float g = tot / (float)N_NODES + bgp[0];
      out_sys[b] = 1.f / (1.f + expf(-g));
    }
  }
}

extern "C" void kernel_launch(void* const* d_in, const int* in_sizes, int n_in,
                              void* d_out, int out_size, void* d_ws, size_t ws_size,
                              hipStream_t stream) {
  (void)in_sizes; (void)n_in; (void)out_size; (void)ws_size;
  const float* nf    = (const float*)d_in[0];
  const int*   src   = (const int*)d_in[3];
  const int*   dst   = (const int*)d_in[4];
  const float* Wne   = (const float*)d_in[5];
  const float* bne   = (const float*)d_in[6];
  const float* Wconv = (const float*)d_in[9];
  const float* bconv = (const float*)d_in[10];
  const float* Wcls  = (const float*)d_in[11];
  const float* bcls  = (const float*)d_in[12];
  const float* Wep   = (const float*)d_in[13];
  const float* bep   = (const float*)d_in[14];
  const float* Wgp   = (const float*)d_in[15];
  const float* bgp   = (const float*)d_in[16];

  char* ws = (char*)d_ws;
  float*  h_f32  = (float*)(ws + 0);
  bf16_t* hs0    = (bf16_t*)(ws + 16777216);
  bf16_t* hs1    = (bf16_t*)(ws + 25165824);
  bf16_t* WneT   = (bf16_t*)(ws + 33554432);
  bf16_t* WconvT = (bf16_t*)(ws + 33554432 + 65536);
  int*    rp     = (int*)(ws + 33554432 + 458752);
  float*  ds     = (float*)(ws + 33554432 + 524288);
  float*  dd     = (float*)(ws + 33554432 + 589824);
  float*  pg     = (float*)(ws + 33554432 + 655360);

  float* out     = (float*)d_out;
  float* out_nh  = out;            // 81920
  float* out_ep  = out + 81920;    // 262144
  float* out_sys = out + 344064;   // 2
  float* out_h   = out + 344066;   // 4194304

  hipLaunchKernelGGL(prep_k, dim3(929), dim3(256), 0, stream, src, rp, Wne, Wconv, WneT, WconvT);
  hipLaunchKernelGGL(gemm1_k, dim3(256, 4), dim3(256), 0, stream, nf, WneT, bne, h_f32, hs0);
  hipLaunchKernelGGL(gconv_k, dim3(1024), dim3(256), 0, stream,
                     hs0, rp, dst, WconvT, bconv, h_f32, hs1);
  hipLaunchKernelGGL(gconv_k, dim3(1024), dim3(256), 0, stream,
                     hs1, rp, dst, WconvT + 65536, bconv + 256, h_f32, hs0);
  hipLaunchKernelGGL(gconv_heads_k, dim3(1024), dim3(256), 0, stream,
                     hs0, rp, dst, WconvT + 131072, bconv + 512, h_f32, out_h,
                     Wcls, bcls, Wep, Wgp, ds, dd, pg, out_nh);
  hipLaunchKernelGGL(edge_sys_k, dim3(1026), dim3(256), 0, stream, ds, dd, src, dst, bep,
                     pg, bgp, out_ep, out_sys);
}